// Round 8
// baseline (167.377 us; speedup 1.0000x reference)
//
#include <hip/hip_runtime.h>

// SpMM: out[b,m] = bias[m] + sum_{e: dst[e]==m} values[e] * x[b, src[e]]
// B=32, N=M=50000, E=1600000.
// v9 (from v8=163.7us, of which ~46us is the harness's 256MB workspace
// re-poison fill — fixed tax, it's inside the timed window).
// Changes: (1) k_bin chunk 8192->16384: per-bucket runs 10.5->21 entries,
// halves scattered-write transactions + reservation rounds; (2) k_gather_rows
// fuses the output transpose: 512-thread blocks own 16 rows, LDS 16x32 tile,
// direct (B,M)-layout write with bias (64B-aligned full lines, zero sharing)
// -> kills k_transpose_out; 8 independent chains (latency-bound at 4).

#define BATCH 32
#define DPB   64              // dsts per bucket -> NB = 782
#define BIN_TPB 1024
#define BIN_EPT 16            // chunk = 16384 edges

// ---- transpose x (B,N) -> xt (N,B), LDS tiled; block 0 also zeros gcount ----
__global__ void k_transpose_x(const float* __restrict__ x, float* __restrict__ xt,
                              int N, int* __restrict__ gcount, int NB) {
    __shared__ float tile[32][33];
    const int n0 = blockIdx.x * 32;
    const int tx = threadIdx.x;   // 0..31
    const int ty = threadIdx.y;   // 0..7
    if (blockIdx.x == 0) {
        const int tid = ty * 32 + tx;
        for (int i = tid; i < NB; i += 256) gcount[i] = 0;
    }
    #pragma unroll
    for (int k = 0; k < 4; ++k) {
        const int b = ty + 8 * k;
        const int n = n0 + tx;
        tile[tx][b] = (n < N) ? x[(size_t)b * N + n] : 0.0f;
    }
    __syncthreads();
    #pragma unroll
    for (int k = 0; k < 4; ++k) {
        const int n = n0 + ty + 8 * k;
        if (n < N) xt[(size_t)n * BATCH + tx] = tile[ty + 8 * k][tx];
    }
}

// ---- per-bucket global histogram via LDS staging ----
__global__ __launch_bounds__(256) void k_bucket_count(const int* __restrict__ idx,
                                                      int* __restrict__ gcount,
                                                      int E, int NB) {
    extern __shared__ int hist[];
    for (int i = threadIdx.x; i < NB; i += blockDim.x) hist[i] = 0;
    __syncthreads();
    const int stride = gridDim.x * blockDim.x;
    for (int e = blockIdx.x * blockDim.x + threadIdx.x; e < E; e += stride) {
        atomicAdd(&hist[idx[E + e] / DPB], 1);
    }
    __syncthreads();
    for (int i = threadIdx.x; i < NB; i += blockDim.x) {
        if (hist[i]) atomicAdd(&gcount[i], hist[i]);
    }
}

// ---- single-wg exclusive scan of bucket counts (NB <= 1024) ----
__global__ __launch_bounds__(1024) void k_scan_buckets(const int* __restrict__ gcount,
                                                       int* __restrict__ bucket_base,
                                                       int* __restrict__ gcursor,
                                                       int NB, int E) {
    __shared__ int s[1024];
    const int tid = threadIdx.x;
    const int v = (tid < NB) ? gcount[tid] : 0;
    s[tid] = v;
    __syncthreads();
    for (int off = 1; off < 1024; off <<= 1) {
        const int t = (tid >= off) ? s[tid - off] : 0;
        __syncthreads();
        s[tid] += t;
        __syncthreads();
    }
    if (tid < NB) {
        const int excl = s[tid] - v;
        bucket_base[tid] = excl;
        gcursor[tid] = excl;
    }
    if (tid == 0) bucket_base[NB] = E;
}

// ---- bin edges into bucket-contiguous segments, packed (src|dl<<16, val) ----
__global__ __launch_bounds__(BIN_TPB) void k_bin(const int* __restrict__ idx,
                                                 const float* __restrict__ values,
                                                 int* __restrict__ gcursor,
                                                 int2* __restrict__ sv,
                                                 int E, int NB) {
    extern __shared__ int lds[];
    int* hist = lds;          // [NB] counts, then reused as local cursor
    int* base = lds + NB;     // [NB] this chunk's global segment base
    for (int i = threadIdx.x; i < NB; i += BIN_TPB) hist[i] = 0;
    __syncthreads();

    const int c0 = blockIdx.x * (BIN_TPB * BIN_EPT);
    int d[BIN_EPT];
    #pragma unroll
    for (int i = 0; i < BIN_EPT; ++i) {
        const int e = c0 + threadIdx.x + i * BIN_TPB;
        d[i] = (e < E) ? idx[E + e] : -1;
        if (d[i] >= 0) atomicAdd(&hist[d[i] / DPB], 1);
    }
    __syncthreads();
    for (int i = threadIdx.x; i < NB; i += BIN_TPB) {
        const int c = hist[i];
        base[i] = c ? atomicAdd(&gcursor[i], c) : 0;
        hist[i] = 0;
    }
    __syncthreads();
    #pragma unroll
    for (int i = 0; i < BIN_EPT; ++i) {
        if (d[i] >= 0) {
            const int e = c0 + threadIdx.x + i * BIN_TPB;
            const int bkt = d[i] / DPB;
            const int off = atomicAdd(&hist[bkt], 1);
            const int packed = (idx[e] & 0xFFFF) | ((d[i] % DPB) << 16);
            sv[base[bkt] + off] = make_int2(packed, __float_as_int(values[e]));
        }
    }
}

// ---- per-bucket counting sort by dst_local: sv -> sv2, emits rowoff[M+1] ----
__global__ __launch_bounds__(1024) void k_sort64(const int2* __restrict__ sv,
                                                 const int* __restrict__ bbase,
                                                 int2* __restrict__ sv2,
                                                 int* __restrict__ rowoff, int M) {
    __shared__ int cnt[DPB];
    __shared__ int off[DPB + 1];
    __shared__ int cur[DPB];
    const int bkt = blockIdx.x;
    const int beg = bbase[bkt];
    const int end = bbase[bkt + 1];
    const int tid = threadIdx.x;
    if (tid < DPB) cnt[tid] = 0;
    __syncthreads();
    for (int i = beg + tid; i < end; i += 1024)
        atomicAdd(&cnt[(sv[i].x >> 16) & 63], 1);
    __syncthreads();
    if (tid < DPB) {   // wave 0: 64-lane shuffle inclusive scan
        const int c = cnt[tid];
        int inc = c;
        #pragma unroll
        for (int dlt = 1; dlt < 64; dlt <<= 1) {
            const int t = __shfl_up(inc, dlt, 64);
            if (tid >= dlt) inc += t;
        }
        off[tid] = inc - c;     // exclusive
        cur[tid] = inc - c;
        if (tid == DPB - 1) off[DPB] = inc;
    }
    __syncthreads();
    for (int i = beg + tid; i < end; i += 1024) {
        const int2 a = sv[i];
        const int p = atomicAdd(&cur[(a.x >> 16) & 63], 1);
        sv2[beg + p] = a;
    }
    // per-dst row offsets (global CSR): rowoff[m0+dl] = beg + off[dl]
    const int m0 = bkt * DPB;
    if (tid <= DPB) {
        const int m = m0 + tid;
        if (tid < DPB && m < M) rowoff[m] = beg + off[tid];
        if (m == M) rowoff[M] = beg + off[tid];   // = E at the last bucket
    }
}

// ---- half-wave per dst row, 8 chains; fused output transpose + bias ----
__global__ __launch_bounds__(512) void k_gather_rows(const int2* __restrict__ sv2,
                                                     const int* __restrict__ rowoff,
                                                     const float* __restrict__ xt,
                                                     const float* __restrict__ bias,
                                                     float* __restrict__ out, int M) {
    __shared__ float tile[16][33];
    const int hw = threadIdx.x >> 5;     // 0..15 (row slot within block)
    const int lb = threadIdx.x & 31;     // batch lane
    const int m0 = blockIdx.x * 16;
    const int m  = m0 + hw;
    float s = 0.0f;
    if (m < M) {
        const int beg = rowoff[m];
        const int end = rowoff[m + 1];
        float a0 = 0.f, a1 = 0.f, a2 = 0.f, a3 = 0.f;
        float a4 = 0.f, a5 = 0.f, a6 = 0.f, a7 = 0.f;
        int i = beg;
        for (; i + 7 < end; i += 8) {    // eight independent chains
            const int2 e0 = sv2[i];
            const int2 e1 = sv2[i + 1];
            const int2 e2 = sv2[i + 2];
            const int2 e3 = sv2[i + 3];
            const int2 e4 = sv2[i + 4];
            const int2 e5 = sv2[i + 5];
            const int2 e6 = sv2[i + 6];
            const int2 e7 = sv2[i + 7];
            const float x0 = xt[(size_t)(e0.x & 0xFFFF) * BATCH + lb];
            const float x1 = xt[(size_t)(e1.x & 0xFFFF) * BATCH + lb];
            const float x2 = xt[(size_t)(e2.x & 0xFFFF) * BATCH + lb];
            const float x3 = xt[(size_t)(e3.x & 0xFFFF) * BATCH + lb];
            const float x4 = xt[(size_t)(e4.x & 0xFFFF) * BATCH + lb];
            const float x5 = xt[(size_t)(e5.x & 0xFFFF) * BATCH + lb];
            const float x6 = xt[(size_t)(e6.x & 0xFFFF) * BATCH + lb];
            const float x7 = xt[(size_t)(e7.x & 0xFFFF) * BATCH + lb];
            a0 += __int_as_float(e0.y) * x0;
            a1 += __int_as_float(e1.y) * x1;
            a2 += __int_as_float(e2.y) * x2;
            a3 += __int_as_float(e3.y) * x3;
            a4 += __int_as_float(e4.y) * x4;
            a5 += __int_as_float(e5.y) * x5;
            a6 += __int_as_float(e6.y) * x6;
            a7 += __int_as_float(e7.y) * x7;
        }
        for (; i < end; ++i) {
            const int2 e0 = sv2[i];
            a0 += __int_as_float(e0.y) * xt[(size_t)(e0.x & 0xFFFF) * BATCH + lb];
        }
        s = ((a0 + a1) + (a2 + a3)) + ((a4 + a5) + (a6 + a7));
    }
    tile[hw][lb] = s;
    __syncthreads();
    // write out (B,M): tid -> b = tid>>4 (0..31), j = tid&15; 64B rows, aligned
    const int b  = threadIdx.x >> 4;
    const int j  = threadIdx.x & 15;
    const int m2 = m0 + j;
    if (m2 < M) out[(size_t)b * M + m2] = tile[j][b] + bias[m2];
}

// ---- fallback (atomic) path ----
__global__ void k_init_out_t(const float* __restrict__ bias, float* __restrict__ out_t, int M) {
    const int i = blockIdx.x * blockDim.x + threadIdx.x;
    if (i < M * BATCH) out_t[i] = bias[i >> 5];
}

__global__ void k_scatter(const float* __restrict__ xt, const float* __restrict__ values,
                          const int* __restrict__ idx, float* __restrict__ out_t, int E) {
    const int t = blockIdx.x * blockDim.x + threadIdx.x;
    const int e = t >> 5;
    const int b = t & 31;
    if (e < E) {
        const int src = idx[e];
        const int dst = idx[E + e];
        const float contrib = values[e] * xt[(size_t)src * BATCH + b];
        atomicAdd(&out_t[(size_t)dst * BATCH + b], contrib);
    }
}

// ---- transpose out_t (M,32) -> out (32,M), LDS tiled (fallback only) ----
__global__ void k_transpose_out(const float* __restrict__ out_t, float* __restrict__ out, int M) {
    __shared__ float tile[32][33];
    const int m0 = blockIdx.x * 32;
    const int tx = threadIdx.x;
    const int ty = threadIdx.y;
    #pragma unroll
    for (int k = 0; k < 4; ++k) {
        const int m = m0 + ty + 8 * k;
        if (m < M) tile[ty + 8 * k][tx] = out_t[(size_t)m * BATCH + tx];
    }
    __syncthreads();
    #pragma unroll
    for (int k = 0; k < 4; ++k) {
        const int b = ty + 8 * k;
        const int m = m0 + tx;
        if (m < M) out[(size_t)b * M + m] = tile[tx][b];
    }
}

extern "C" void kernel_launch(void* const* d_in, const int* in_sizes, int n_in,
                              void* d_out, int out_size, void* d_ws, size_t ws_size,
                              hipStream_t stream) {
    const float* x      = (const float*)d_in[0];  // (B,N,1) fp32
    const float* values = (const float*)d_in[1];  // (E,)    fp32
    const float* bias   = (const float*)d_in[2];  // (M,1)   fp32
    const int*   idx    = (const int*)d_in[3];    // (2,E)   int32

    const int N = in_sizes[0] / BATCH;   // 50000
    const int E = in_sizes[3] / 2;       // 1600000
    const int M = in_sizes[2];           // 50000
    const int NB = (M + DPB - 1) / DPB;  // 782

    float* out = (float*)d_out;

    // ---- workspace carve (512B aligned); fallback needs only xt+out_t ----
    char* base = (char*)d_ws;
    size_t off = 0;
    auto carve = [&](size_t bytes) -> void* {
        void* r = base + off;
        off = (off + bytes + 511) & ~(size_t)511;
        return r;
    };
    float* xt      = (float*)carve((size_t)N * BATCH * sizeof(float));  // 6.4 MB
    float* out_t   = (float*)carve((size_t)M * BATCH * sizeof(float));  // 6.4 MB
    int2*  sv      = (int2*)carve((size_t)E * sizeof(int2));            // 12.8 MB
    int2*  sv2     = (int2*)carve((size_t)E * sizeof(int2));            // 12.8 MB
    int*   gcount  = (int*)carve((size_t)NB * sizeof(int));
    int*   bbase   = (int*)carve((size_t)(NB + 1) * sizeof(int));
    int*   gcursor = (int*)carve((size_t)NB * sizeof(int));
    int*   rowoff  = (int*)carve((size_t)(M + 1) * sizeof(int));
    const size_t csr_needed = off;

    dim3 tblk(32, 8);
    k_transpose_x<<<(N + 31) / 32, tblk, 0, stream>>>(x, xt, N, gcount, NB);

    const bool use_csr = (csr_needed <= ws_size) && (N <= 65536) && (NB <= 1024);
    if (use_csr) {
        const size_t hist_bytes = (size_t)NB * sizeof(int);
        k_bucket_count<<<512, 256, hist_bytes, stream>>>(idx, gcount, E, NB);
        k_scan_buckets<<<1, 1024, 0, stream>>>(gcount, bbase, gcursor, NB, E);
        const int chunk = BIN_TPB * BIN_EPT;
        k_bin<<<(E + chunk - 1) / chunk, BIN_TPB, 2 * hist_bytes, stream>>>(idx, values, gcursor, sv, E, NB);
        k_sort64<<<NB, 1024, 0, stream>>>(sv, bbase, sv2, rowoff, M);
        k_gather_rows<<<(M + 15) / 16, 512, 0, stream>>>(sv2, rowoff, xt, bias, out, M);
    } else {
        // fallback: proven atomic path
        k_init_out_t<<<(M * BATCH + 255) / 256, 256, 0, stream>>>(bias, out_t, M);
        const long long total = (long long)E * BATCH;
        k_scatter<<<(int)((total + 255) / 256), 256, 0, stream>>>(xt, values, idx, out_t, E);
        k_transpose_out<<<(M + 31) / 32, tblk, 0, stream>>>(out_t, out, M);
    }
}

// Round 9
// 160.145 us; speedup vs baseline: 1.0452x; 1.0452x over previous
//
#include <hip/hip_runtime.h>

// SpMM: out[b,m] = bias[m] + sum_{e: dst[e]==m} values[e] * x[b, src[e]]
// B=32, N=M=50000, E=1600000.
// v10 (from v9=167.4us). Round-8 post-mortem: k_bin ~40us floor independent
// of grid/run-length -> L2 line-op bound (1.6M scattered 8B stores = 1.6M
// line touches). Fix: counting-sort each 4096-edge chunk by bucket in LDS
// (recording final global index per entry), then linear COALESCED write-out
// (runs of ~21 entries, consecutive lanes -> consecutive addresses).
// DPB 64->256 (NB=196) keeps runs long at chunk 4096. Sort adapts to 256
// dsts/bucket. Gather (half-wave/row, 8 chains, fused transpose) unchanged.

#define BATCH 32
#define DPB   256             // dsts per bucket -> NB = 196
#define NB_MAX 256
#define BIN_TPB 1024
#define BIN_CHUNK 4096
#define BIN_EPT 4             // BIN_CHUNK / BIN_TPB

// ---- transpose x (B,N) -> xt (N,B), LDS tiled; block 0 also zeros gcount ----
__global__ void k_transpose_x(const float* __restrict__ x, float* __restrict__ xt,
                              int N, int* __restrict__ gcount, int NB) {
    __shared__ float tile[32][33];
    const int n0 = blockIdx.x * 32;
    const int tx = threadIdx.x;   // 0..31
    const int ty = threadIdx.y;   // 0..7
    if (blockIdx.x == 0) {
        const int tid = ty * 32 + tx;
        for (int i = tid; i < NB; i += 256) gcount[i] = 0;
    }
    #pragma unroll
    for (int k = 0; k < 4; ++k) {
        const int b = ty + 8 * k;
        const int n = n0 + tx;
        tile[tx][b] = (n < N) ? x[(size_t)b * N + n] : 0.0f;
    }
    __syncthreads();
    #pragma unroll
    for (int k = 0; k < 4; ++k) {
        const int n = n0 + ty + 8 * k;
        if (n < N) xt[(size_t)n * BATCH + tx] = tile[ty + 8 * k][tx];
    }
}

// ---- per-bucket global histogram via LDS staging ----
__global__ __launch_bounds__(256) void k_bucket_count(const int* __restrict__ idx,
                                                      int* __restrict__ gcount,
                                                      int E, int NB) {
    __shared__ int hist[NB_MAX];
    for (int i = threadIdx.x; i < NB; i += blockDim.x) hist[i] = 0;
    __syncthreads();
    const int stride = gridDim.x * blockDim.x;
    for (int e = blockIdx.x * blockDim.x + threadIdx.x; e < E; e += stride) {
        atomicAdd(&hist[idx[E + e] >> 8], 1);   // /DPB (256)
    }
    __syncthreads();
    for (int i = threadIdx.x; i < NB; i += blockDim.x) {
        if (hist[i]) atomicAdd(&gcount[i], hist[i]);
    }
}

// ---- single-wg exclusive scan of bucket counts (NB <= 1024) ----
__global__ __launch_bounds__(1024) void k_scan_buckets(const int* __restrict__ gcount,
                                                       int* __restrict__ bucket_base,
                                                       int* __restrict__ gcursor,
                                                       int NB, int E) {
    __shared__ int s[1024];
    const int tid = threadIdx.x;
    const int v = (tid < NB) ? gcount[tid] : 0;
    s[tid] = v;
    __syncthreads();
    for (int off = 1; off < 1024; off <<= 1) {
        const int t = (tid >= off) ? s[tid - off] : 0;
        __syncthreads();
        s[tid] += t;
        __syncthreads();
    }
    if (tid < NB) {
        const int excl = s[tid] - v;
        bucket_base[tid] = excl;
        gcursor[tid] = excl;
    }
    if (tid == 0) bucket_base[NB] = E;
}

// ---- bin: LDS counting-sort each chunk by bucket, coalesced write-out ----
__global__ __launch_bounds__(BIN_TPB) void k_bin(const int* __restrict__ idx,
                                                 const float* __restrict__ values,
                                                 int* __restrict__ gcursor,
                                                 int2* __restrict__ sv,
                                                 int E, int NB) {
    __shared__ int  hist[NB_MAX];     // counts, then per-bucket cursor
    __shared__ int  loff[NB_MAX];     // chunk-local exclusive offsets
    __shared__ int  gbase[NB_MAX];    // this chunk's global segment base
    __shared__ int2 svl[BIN_CHUNK];   // chunk sorted by bucket (32 KB)
    __shared__ int  gidx[BIN_CHUNK];  // final global index per slot (16 KB)
    const int tid = threadIdx.x;
    if (tid < NB) hist[tid] = 0;
    __syncthreads();

    const int c0 = blockIdx.x * BIN_CHUNK;
    const int nE = min(BIN_CHUNK, E - c0);
    int d[BIN_EPT];
    #pragma unroll
    for (int i = 0; i < BIN_EPT; ++i) {
        const int e = c0 + tid + i * BIN_TPB;
        d[i] = (e < E) ? idx[E + e] : -1;
        if (d[i] >= 0) atomicAdd(&hist[d[i] >> 8], 1);
    }
    __syncthreads();
    // wave 0: exclusive scan of NB counts (64-lane chunks with carry)
    if (tid < 64) {
        int carry = 0;
        for (int c = 0; c < NB; c += 64) {
            const int j = c + tid;
            const int v = (j < NB) ? hist[j] : 0;
            int inc = v;
            #pragma unroll
            for (int dlt = 1; dlt < 64; dlt <<= 1) {
                const int t = __shfl_up(inc, dlt, 64);
                if (tid >= dlt) inc += t;
            }
            if (j < NB) loff[j] = carry + inc - v;
            carry += __shfl(inc, 63, 64);
        }
    }
    __syncthreads();
    // reserve global segments; reset cursors
    if (tid < NB) {
        const int c = hist[tid];
        gbase[tid] = c ? atomicAdd(&gcursor[tid], c) : 0;
        hist[tid] = 0;
    }
    __syncthreads();
    // scatter into LDS sorted order + record final global index
    #pragma unroll
    for (int i = 0; i < BIN_EPT; ++i) {
        if (d[i] >= 0) {
            const int e = c0 + tid + i * BIN_TPB;
            const int bkt = d[i] >> 8;
            const int off = atomicAdd(&hist[bkt], 1);
            const int slot = loff[bkt] + off;
            const int packed = (idx[e] & 0xFFFF) | ((d[i] & 255) << 16);
            svl[slot]  = make_int2(packed, __float_as_int(values[e]));
            gidx[slot] = gbase[bkt] + off;
        }
    }
    __syncthreads();
    // coalesced write-out: consecutive slots -> consecutive global addresses
    for (int s = tid; s < nE; s += BIN_TPB) {
        sv[gidx[s]] = svl[s];
    }
}

// ---- per-bucket counting sort by dst_local: sv -> sv2, emits rowoff[M+1] ----
__global__ __launch_bounds__(1024) void k_sort(const int2* __restrict__ sv,
                                               const int* __restrict__ bbase,
                                               int2* __restrict__ sv2,
                                               int* __restrict__ rowoff, int M) {
    __shared__ int cnt[DPB];
    __shared__ int off[DPB + 1];
    __shared__ int cur[DPB];
    const int bkt = blockIdx.x;
    const int beg = bbase[bkt];
    const int end = bbase[bkt + 1];
    const int tid = threadIdx.x;
    for (int t = tid; t < DPB; t += 1024) cnt[t] = 0;
    __syncthreads();
    for (int i = beg + tid; i < end; i += 1024)
        atomicAdd(&cnt[(sv[i].x >> 16) & 255], 1);
    __syncthreads();
    if (tid < 64) {   // wave 0: scan 256 counts in 4 chunks with carry
        int carry = 0;
        #pragma unroll
        for (int c = 0; c < DPB; c += 64) {
            const int j = c + tid;
            const int v = cnt[j];
            int inc = v;
            #pragma unroll
            for (int dlt = 1; dlt < 64; dlt <<= 1) {
                const int t = __shfl_up(inc, dlt, 64);
                if (tid >= dlt) inc += t;
            }
            off[j] = carry + inc - v;
            cur[j] = carry + inc - v;
            carry += __shfl(inc, 63, 64);
        }
        if (tid == 0) off[DPB] = carry;
    }
    __syncthreads();
    for (int i = beg + tid; i < end; i += 1024) {
        const int2 a = sv[i];
        const int p = atomicAdd(&cur[(a.x >> 16) & 255], 1);
        sv2[beg + p] = a;
    }
    // per-dst row offsets (global CSR)
    const int m0 = bkt * DPB;
    for (int t = tid; t <= DPB; t += 1024) {
        const int m = m0 + t;
        if (t < DPB && m < M) rowoff[m] = beg + off[t];
        if (m == M) rowoff[M] = beg + off[t];
    }
}

// ---- half-wave per dst row, 8 chains; fused output transpose + bias ----
__global__ __launch_bounds__(512) void k_gather_rows(const int2* __restrict__ sv2,
                                                     const int* __restrict__ rowoff,
                                                     const float* __restrict__ xt,
                                                     const float* __restrict__ bias,
                                                     float* __restrict__ out, int M) {
    __shared__ float tile[16][33];
    const int hw = threadIdx.x >> 5;     // 0..15 (row slot within block)
    const int lb = threadIdx.x & 31;     // batch lane
    const int m0 = blockIdx.x * 16;
    const int m  = m0 + hw;
    float s = 0.0f;
    if (m < M) {
        const int beg = rowoff[m];
        const int end = rowoff[m + 1];
        float a0 = 0.f, a1 = 0.f, a2 = 0.f, a3 = 0.f;
        float a4 = 0.f, a5 = 0.f, a6 = 0.f, a7 = 0.f;
        int i = beg;
        for (; i + 7 < end; i += 8) {    // eight independent chains
            const int2 e0 = sv2[i];
            const int2 e1 = sv2[i + 1];
            const int2 e2 = sv2[i + 2];
            const int2 e3 = sv2[i + 3];
            const int2 e4 = sv2[i + 4];
            const int2 e5 = sv2[i + 5];
            const int2 e6 = sv2[i + 6];
            const int2 e7 = sv2[i + 7];
            const float x0 = xt[(size_t)(e0.x & 0xFFFF) * BATCH + lb];
            const float x1 = xt[(size_t)(e1.x & 0xFFFF) * BATCH + lb];
            const float x2 = xt[(size_t)(e2.x & 0xFFFF) * BATCH + lb];
            const float x3 = xt[(size_t)(e3.x & 0xFFFF) * BATCH + lb];
            const float x4 = xt[(size_t)(e4.x & 0xFFFF) * BATCH + lb];
            const float x5 = xt[(size_t)(e5.x & 0xFFFF) * BATCH + lb];
            const float x6 = xt[(size_t)(e6.x & 0xFFFF) * BATCH + lb];
            const float x7 = xt[(size_t)(e7.x & 0xFFFF) * BATCH + lb];
            a0 += __int_as_float(e0.y) * x0;
            a1 += __int_as_float(e1.y) * x1;
            a2 += __int_as_float(e2.y) * x2;
            a3 += __int_as_float(e3.y) * x3;
            a4 += __int_as_float(e4.y) * x4;
            a5 += __int_as_float(e5.y) * x5;
            a6 += __int_as_float(e6.y) * x6;
            a7 += __int_as_float(e7.y) * x7;
        }
        for (; i < end; ++i) {
            const int2 e0 = sv2[i];
            a0 += __int_as_float(e0.y) * xt[(size_t)(e0.x & 0xFFFF) * BATCH + lb];
        }
        s = ((a0 + a1) + (a2 + a3)) + ((a4 + a5) + (a6 + a7));
    }
    tile[hw][lb] = s;
    __syncthreads();
    // write out (B,M): tid -> b = tid>>4 (0..31), j = tid&15; 64B rows, aligned
    const int b  = threadIdx.x >> 4;
    const int j  = threadIdx.x & 15;
    const int m2 = m0 + j;
    if (m2 < M) out[(size_t)b * M + m2] = tile[j][b] + bias[m2];
}

// ---- fallback (atomic) path ----
__global__ void k_init_out_t(const float* __restrict__ bias, float* __restrict__ out_t, int M) {
    const int i = blockIdx.x * blockDim.x + threadIdx.x;
    if (i < M * BATCH) out_t[i] = bias[i >> 5];
}

__global__ void k_scatter(const float* __restrict__ xt, const float* __restrict__ values,
                          const int* __restrict__ idx, float* __restrict__ out_t, int E) {
    const int t = blockIdx.x * blockDim.x + threadIdx.x;
    const int e = t >> 5;
    const int b = t & 31;
    if (e < E) {
        const int src = idx[e];
        const int dst = idx[E + e];
        const float contrib = values[e] * xt[(size_t)src * BATCH + b];
        atomicAdd(&out_t[(size_t)dst * BATCH + b], contrib);
    }
}

// ---- transpose out_t (M,32) -> out (32,M), LDS tiled (fallback only) ----
__global__ void k_transpose_out(const float* __restrict__ out_t, float* __restrict__ out, int M) {
    __shared__ float tile[32][33];
    const int m0 = blockIdx.x * 32;
    const int tx = threadIdx.x;
    const int ty = threadIdx.y;
    #pragma unroll
    for (int k = 0; k < 4; ++k) {
        const int m = m0 + ty + 8 * k;
        if (m < M) tile[ty + 8 * k][tx] = out_t[(size_t)m * BATCH + tx];
    }
    __syncthreads();
    #pragma unroll
    for (int k = 0; k < 4; ++k) {
        const int b = ty + 8 * k;
        const int m = m0 + tx;
        if (m < M) out[(size_t)b * M + m] = tile[tx][b];
    }
}

extern "C" void kernel_launch(void* const* d_in, const int* in_sizes, int n_in,
                              void* d_out, int out_size, void* d_ws, size_t ws_size,
                              hipStream_t stream) {
    const float* x      = (const float*)d_in[0];  // (B,N,1) fp32
    const float* values = (const float*)d_in[1];  // (E,)    fp32
    const float* bias   = (const float*)d_in[2];  // (M,1)   fp32
    const int*   idx    = (const int*)d_in[3];    // (2,E)   int32

    const int N = in_sizes[0] / BATCH;   // 50000
    const int E = in_sizes[3] / 2;       // 1600000
    const int M = in_sizes[2];           // 50000
    const int NB = (M + DPB - 1) / DPB;  // 196

    float* out = (float*)d_out;

    // ---- workspace carve (512B aligned); fallback needs only xt+out_t ----
    char* base = (char*)d_ws;
    size_t off = 0;
    auto carve = [&](size_t bytes) -> void* {
        void* r = base + off;
        off = (off + bytes + 511) & ~(size_t)511;
        return r;
    };
    float* xt      = (float*)carve((size_t)N * BATCH * sizeof(float));  // 6.4 MB
    float* out_t   = (float*)carve((size_t)M * BATCH * sizeof(float));  // 6.4 MB
    int2*  sv      = (int2*)carve((size_t)E * sizeof(int2));            // 12.8 MB
    int2*  sv2     = (int2*)carve((size_t)E * sizeof(int2));            // 12.8 MB
    int*   gcount  = (int*)carve((size_t)NB * sizeof(int));
    int*   bbase   = (int*)carve((size_t)(NB + 1) * sizeof(int));
    int*   gcursor = (int*)carve((size_t)NB * sizeof(int));
    int*   rowoff  = (int*)carve((size_t)(M + 1) * sizeof(int));
    const size_t csr_needed = off;

    dim3 tblk(32, 8);
    k_transpose_x<<<(N + 31) / 32, tblk, 0, stream>>>(x, xt, N, gcount, NB);

    const bool use_csr = (csr_needed <= ws_size) && (N <= 65536) && (M <= 65536)
                         && (NB <= NB_MAX);
    if (use_csr) {
        k_bucket_count<<<512, 256, 0, stream>>>(idx, gcount, E, NB);
        k_scan_buckets<<<1, 1024, 0, stream>>>(gcount, bbase, gcursor, NB, E);
        k_bin<<<(E + BIN_CHUNK - 1) / BIN_CHUNK, BIN_TPB, 0, stream>>>(idx, values, gcursor, sv, E, NB);
        k_sort<<<NB, 1024, 0, stream>>>(sv, bbase, sv2, rowoff, M);
        k_gather_rows<<<(M + 15) / 16, 512, 0, stream>>>(sv2, rowoff, xt, bias, out, M);
    } else {
        // fallback: proven atomic path
        k_init_out_t<<<(M * BATCH + 255) / 256, 256, 0, stream>>>(bias, out_t, M);
        const long long total = (long long)E * BATCH;
        k_scatter<<<(int)((total + 255) / 256), 256, 0, stream>>>(xt, values, idx, out_t, E);
        k_transpose_out<<<(M + 31) / 32, tblk, 0, stream>>>(out_t, out, M);
    }
}

// Round 10
// 153.082 us; speedup vs baseline: 1.0934x; 1.0461x over previous
//
#include <hip/hip_runtime.h>

// SpMM: out[b,m] = bias[m] + sum_{e: dst[e]==m} values[e] * x[b, src[e]]
// B=32, N=M=50000, E=1600000.
// v11 (from v10=160.1us; ~45us of that is the harness's workspace re-poison
// fill, a fixed tax). Levers: (1) gather rebuilt as one WAVE per row with
// float4 lanes: 8 lanes x 16B cover an xt row in ONE instruction, 8 edges per
// wave-instruction pair, 2 independent chains, shfl_xor(8/16/32) cross-group
// reduce -> 8x fewer VMEM issue slots at identical traffic. (2) DPB 256->128:
// sort 196->391 blocks (1.5/CU), bin runs ~10.5 entries (still >= 1 line).

#define BATCH 32
#define DPB   128             // dsts per bucket -> NB = 391
#define NB_MAX 400
#define BIN_TPB 1024
#define BIN_CHUNK 4096
#define BIN_EPT 4             // BIN_CHUNK / BIN_TPB

// ---- transpose x (B,N) -> xt (N,B), LDS tiled; block 0 also zeros gcount ----
__global__ void k_transpose_x(const float* __restrict__ x, float* __restrict__ xt,
                              int N, int* __restrict__ gcount, int NB) {
    __shared__ float tile[32][33];
    const int n0 = blockIdx.x * 32;
    const int tx = threadIdx.x;   // 0..31
    const int ty = threadIdx.y;   // 0..7
    if (blockIdx.x == 0) {
        const int tid = ty * 32 + tx;
        for (int i = tid; i < NB; i += 256) gcount[i] = 0;
    }
    #pragma unroll
    for (int k = 0; k < 4; ++k) {
        const int b = ty + 8 * k;
        const int n = n0 + tx;
        tile[tx][b] = (n < N) ? x[(size_t)b * N + n] : 0.0f;
    }
    __syncthreads();
    #pragma unroll
    for (int k = 0; k < 4; ++k) {
        const int n = n0 + ty + 8 * k;
        if (n < N) xt[(size_t)n * BATCH + tx] = tile[ty + 8 * k][tx];
    }
}

// ---- per-bucket global histogram via LDS staging ----
__global__ __launch_bounds__(256) void k_bucket_count(const int* __restrict__ idx,
                                                      int* __restrict__ gcount,
                                                      int E, int NB) {
    __shared__ int hist[NB_MAX];
    for (int i = threadIdx.x; i < NB; i += blockDim.x) hist[i] = 0;
    __syncthreads();
    const int stride = gridDim.x * blockDim.x;
    for (int e = blockIdx.x * blockDim.x + threadIdx.x; e < E; e += stride) {
        atomicAdd(&hist[idx[E + e] >> 7], 1);   // /DPB (128)
    }
    __syncthreads();
    for (int i = threadIdx.x; i < NB; i += blockDim.x) {
        if (hist[i]) atomicAdd(&gcount[i], hist[i]);
    }
}

// ---- single-wg exclusive scan of bucket counts (NB <= 1024) ----
__global__ __launch_bounds__(1024) void k_scan_buckets(const int* __restrict__ gcount,
                                                       int* __restrict__ bucket_base,
                                                       int* __restrict__ gcursor,
                                                       int NB, int E) {
    __shared__ int s[1024];
    const int tid = threadIdx.x;
    const int v = (tid < NB) ? gcount[tid] : 0;
    s[tid] = v;
    __syncthreads();
    for (int off = 1; off < 1024; off <<= 1) {
        const int t = (tid >= off) ? s[tid - off] : 0;
        __syncthreads();
        s[tid] += t;
        __syncthreads();
    }
    if (tid < NB) {
        const int excl = s[tid] - v;
        bucket_base[tid] = excl;
        gcursor[tid] = excl;
    }
    if (tid == 0) bucket_base[NB] = E;
}

// ---- bin: LDS counting-sort each chunk by bucket, coalesced write-out ----
__global__ __launch_bounds__(BIN_TPB) void k_bin(const int* __restrict__ idx,
                                                 const float* __restrict__ values,
                                                 int* __restrict__ gcursor,
                                                 int2* __restrict__ sv,
                                                 int E, int NB) {
    __shared__ int  hist[NB_MAX];     // counts, then per-bucket cursor
    __shared__ int  loff[NB_MAX];     // chunk-local exclusive offsets
    __shared__ int  gbase[NB_MAX];    // this chunk's global segment base
    __shared__ int2 svl[BIN_CHUNK];   // chunk sorted by bucket (32 KB)
    __shared__ int  gidx[BIN_CHUNK];  // final global index per slot (16 KB)
    const int tid = threadIdx.x;
    if (tid < NB) hist[tid] = 0;
    __syncthreads();

    const int c0 = blockIdx.x * BIN_CHUNK;
    const int nE = min(BIN_CHUNK, E - c0);
    int d[BIN_EPT];
    #pragma unroll
    for (int i = 0; i < BIN_EPT; ++i) {
        const int e = c0 + tid + i * BIN_TPB;
        d[i] = (e < E) ? idx[E + e] : -1;
        if (d[i] >= 0) atomicAdd(&hist[d[i] >> 7], 1);
    }
    __syncthreads();
    // wave 0: exclusive scan of NB counts (64-lane chunks with carry)
    if (tid < 64) {
        int carry = 0;
        for (int c = 0; c < NB; c += 64) {
            const int j = c + tid;
            const int v = (j < NB) ? hist[j] : 0;
            int inc = v;
            #pragma unroll
            for (int dlt = 1; dlt < 64; dlt <<= 1) {
                const int t = __shfl_up(inc, dlt, 64);
                if (tid >= dlt) inc += t;
            }
            if (j < NB) loff[j] = carry + inc - v;
            carry += __shfl(inc, 63, 64);
        }
    }
    __syncthreads();
    // reserve global segments; reset cursors
    if (tid < NB) {
        const int c = hist[tid];
        gbase[tid] = c ? atomicAdd(&gcursor[tid], c) : 0;
        hist[tid] = 0;
    }
    __syncthreads();
    // scatter into LDS sorted order + record final global index
    #pragma unroll
    for (int i = 0; i < BIN_EPT; ++i) {
        if (d[i] >= 0) {
            const int e = c0 + tid + i * BIN_TPB;
            const int bkt = d[i] >> 7;
            const int off = atomicAdd(&hist[bkt], 1);
            const int slot = loff[bkt] + off;
            const int packed = (idx[e] & 0xFFFF) | ((d[i] & 127) << 16);
            svl[slot]  = make_int2(packed, __float_as_int(values[e]));
            gidx[slot] = gbase[bkt] + off;
        }
    }
    __syncthreads();
    // coalesced write-out: consecutive slots -> consecutive global addresses
    for (int s = tid; s < nE; s += BIN_TPB) {
        sv[gidx[s]] = svl[s];
    }
}

// ---- per-bucket counting sort by dst_local: sv -> sv2, emits rowoff[M+1] ----
__global__ __launch_bounds__(1024) void k_sort(const int2* __restrict__ sv,
                                               const int* __restrict__ bbase,
                                               int2* __restrict__ sv2,
                                               int* __restrict__ rowoff, int M) {
    __shared__ int cnt[DPB];
    __shared__ int off[DPB + 1];
    __shared__ int cur[DPB];
    const int bkt = blockIdx.x;
    const int beg = bbase[bkt];
    const int end = bbase[bkt + 1];
    const int tid = threadIdx.x;
    for (int t = tid; t < DPB; t += 1024) cnt[t] = 0;
    __syncthreads();
    for (int i = beg + tid; i < end; i += 1024)
        atomicAdd(&cnt[(sv[i].x >> 16) & 127], 1);
    __syncthreads();
    if (tid < 64) {   // wave 0: scan DPB counts in 64-lane chunks with carry
        int carry = 0;
        #pragma unroll
        for (int c = 0; c < DPB; c += 64) {
            const int j = c + tid;
            const int v = cnt[j];
            int inc = v;
            #pragma unroll
            for (int dlt = 1; dlt < 64; dlt <<= 1) {
                const int t = __shfl_up(inc, dlt, 64);
                if (tid >= dlt) inc += t;
            }
            off[j] = carry + inc - v;
            cur[j] = carry + inc - v;
            carry += __shfl(inc, 63, 64);
        }
        if (tid == 0) off[DPB] = carry;
    }
    __syncthreads();
    for (int i = beg + tid; i < end; i += 1024) {
        const int2 a = sv[i];
        const int p = atomicAdd(&cur[(a.x >> 16) & 127], 1);
        sv2[beg + p] = a;
    }
    // per-dst row offsets (global CSR)
    const int m0 = bkt * DPB;
    for (int t = tid; t <= DPB; t += 1024) {
        const int m = m0 + t;
        if (t < DPB && m < M) rowoff[m] = beg + off[t];
        if (m == M) rowoff[M] = beg + off[t];
    }
}

// ---- one WAVE per dst row: float4 lanes, 8 edges/wave-instr, shfl reduce ----
// lane: g = lane>>3 selects edge within group-of-8, j = lane&7 selects 16B of
// the 128B xt row. Cross-group reduce via shfl_xor(8,16,32). Fused transpose.
__global__ __launch_bounds__(1024) void k_gather_rows(const int2* __restrict__ sv2,
                                                      const int* __restrict__ rowoff,
                                                      const float* __restrict__ xt,
                                                      const float* __restrict__ bias,
                                                      float* __restrict__ out, int M) {
    __shared__ float tile[16][33];
    const int w    = threadIdx.x >> 6;   // wave 0..15 -> row slot
    const int lane = threadIdx.x & 63;
    const int g    = lane >> 3;          // 0..7 edge slot
    const int j    = lane & 7;           // 16B slice of row
    const int m0   = blockIdx.x * 16;
    const int m    = m0 + w;
    const float4* __restrict__ xt4 = (const float4*)xt;

    float ax = 0.f, ay = 0.f, az = 0.f, aw = 0.f;
    float bx2 = 0.f, by2 = 0.f, bz2 = 0.f, bw2 = 0.f;
    if (m < M) {
        const int beg = rowoff[m];
        const int end = rowoff[m + 1];
        int i = beg;
        for (; i + 15 < end; i += 16) {   // 2 chains x 8 edges
            const int2 eA = sv2[i + g];
            const int2 eB = sv2[i + 8 + g];
            const float4 xA = xt4[(size_t)(eA.x & 0xFFFF) * 8 + j];
            const float4 xB = xt4[(size_t)(eB.x & 0xFFFF) * 8 + j];
            const float vA = __int_as_float(eA.y);
            const float vB = __int_as_float(eB.y);
            ax += vA * xA.x; ay += vA * xA.y; az += vA * xA.z; aw += vA * xA.w;
            bx2 += vB * xB.x; by2 += vB * xB.y; bz2 += vB * xB.z; bw2 += vB * xB.w;
        }
        for (; i < end; i += 8) {          // ragged tail, predicated per group
            if (i + g < end) {
                const int2 e = sv2[i + g];
                const float4 xv = xt4[(size_t)(e.x & 0xFFFF) * 8 + j];
                const float v = __int_as_float(e.y);
                ax += v * xv.x; ay += v * xv.y; az += v * xv.z; aw += v * xv.w;
            }
        }
    }
    ax += bx2; ay += by2; az += bz2; aw += bw2;
    // reduce across the 8 groups (lane bits 3,4,5)
    #pragma unroll
    for (int d = 8; d < 64; d <<= 1) {
        ax += __shfl_xor(ax, d, 64);
        ay += __shfl_xor(ay, d, 64);
        az += __shfl_xor(az, d, 64);
        aw += __shfl_xor(aw, d, 64);
    }
    if (g == 0) {   // lanes 0..7 hold the row's 32 floats as float4
        tile[w][j * 4 + 0] = ax;
        tile[w][j * 4 + 1] = ay;
        tile[w][j * 4 + 2] = az;
        tile[w][j * 4 + 3] = aw;
    }
    __syncthreads();
    // write out (B,M): 512 threads -> b = tid>>4, jj = tid&15; 64B rows
    if (threadIdx.x < 512) {
        const int b  = threadIdx.x >> 4;
        const int jj = threadIdx.x & 15;
        const int m2 = m0 + jj;
        if (m2 < M) out[(size_t)b * M + m2] = tile[jj][b] + bias[m2];
    }
}

// ---- fallback (atomic) path ----
__global__ void k_init_out_t(const float* __restrict__ bias, float* __restrict__ out_t, int M) {
    const int i = blockIdx.x * blockDim.x + threadIdx.x;
    if (i < M * BATCH) out_t[i] = bias[i >> 5];
}

__global__ void k_scatter(const float* __restrict__ xt, const float* __restrict__ values,
                          const int* __restrict__ idx, float* __restrict__ out_t, int E) {
    const int t = blockIdx.x * blockDim.x + threadIdx.x;
    const int e = t >> 5;
    const int b = t & 31;
    if (e < E) {
        const int src = idx[e];
        const int dst = idx[E + e];
        const float contrib = values[e] * xt[(size_t)src * BATCH + b];
        atomicAdd(&out_t[(size_t)dst * BATCH + b], contrib);
    }
}

// ---- transpose out_t (M,32) -> out (32,M), LDS tiled (fallback only) ----
__global__ void k_transpose_out(const float* __restrict__ out_t, float* __restrict__ out, int M) {
    __shared__ float tile[32][33];
    const int m0 = blockIdx.x * 32;
    const int tx = threadIdx.x;
    const int ty = threadIdx.y;
    #pragma unroll
    for (int k = 0; k < 4; ++k) {
        const int m = m0 + ty + 8 * k;
        if (m < M) tile[ty + 8 * k][tx] = out_t[(size_t)m * BATCH + tx];
    }
    __syncthreads();
    #pragma unroll
    for (int k = 0; k < 4; ++k) {
        const int b = ty + 8 * k;
        const int m = m0 + tx;
        if (m < M) out[(size_t)b * M + m] = tile[tx][b];
    }
}

extern "C" void kernel_launch(void* const* d_in, const int* in_sizes, int n_in,
                              void* d_out, int out_size, void* d_ws, size_t ws_size,
                              hipStream_t stream) {
    const float* x      = (const float*)d_in[0];  // (B,N,1) fp32
    const float* values = (const float*)d_in[1];  // (E,)    fp32
    const float* bias   = (const float*)d_in[2];  // (M,1)   fp32
    const int*   idx    = (const int*)d_in[3];    // (2,E)   int32

    const int N = in_sizes[0] / BATCH;   // 50000
    const int E = in_sizes[3] / 2;       // 1600000
    const int M = in_sizes[2];           // 50000
    const int NB = (M + DPB - 1) / DPB;  // 391

    float* out = (float*)d_out;

    // ---- workspace carve (512B aligned); fallback needs only xt+out_t ----
    char* base = (char*)d_ws;
    size_t off = 0;
    auto carve = [&](size_t bytes) -> void* {
        void* r = base + off;
        off = (off + bytes + 511) & ~(size_t)511;
        return r;
    };
    float* xt      = (float*)carve((size_t)N * BATCH * sizeof(float));  // 6.4 MB
    float* out_t   = (float*)carve((size_t)M * BATCH * sizeof(float));  // 6.4 MB
    int2*  sv      = (int2*)carve((size_t)E * sizeof(int2));            // 12.8 MB
    int2*  sv2     = (int2*)carve((size_t)E * sizeof(int2));            // 12.8 MB
    int*   gcount  = (int*)carve((size_t)NB * sizeof(int));
    int*   bbase   = (int*)carve((size_t)(NB + 1) * sizeof(int));
    int*   gcursor = (int*)carve((size_t)NB * sizeof(int));
    int*   rowoff  = (int*)carve((size_t)(M + 1) * sizeof(int));
    const size_t csr_needed = off;

    dim3 tblk(32, 8);
    k_transpose_x<<<(N + 31) / 32, tblk, 0, stream>>>(x, xt, N, gcount, NB);

    const bool use_csr = (csr_needed <= ws_size) && (N <= 65536) && (M <= 65536)
                         && (NB <= NB_MAX);
    if (use_csr) {
        k_bucket_count<<<512, 256, 0, stream>>>(idx, gcount, E, NB);
        k_scan_buckets<<<1, 1024, 0, stream>>>(gcount, bbase, gcursor, NB, E);
        k_bin<<<(E + BIN_CHUNK - 1) / BIN_CHUNK, BIN_TPB, 0, stream>>>(idx, values, gcursor, sv, E, NB);
        k_sort<<<NB, 1024, 0, stream>>>(sv, bbase, sv2, rowoff, M);
        k_gather_rows<<<(M + 15) / 16, 1024, 0, stream>>>(sv2, rowoff, xt, bias, out, M);
    } else {
        // fallback: proven atomic path
        k_init_out_t<<<(M * BATCH + 255) / 256, 256, 0, stream>>>(bias, out_t, M);
        const long long total = (long long)E * BATCH;
        k_scatter<<<(int)((total + 255) / 256), 256, 0, stream>>>(xt, values, idx, out_t, E);
        k_transpose_out<<<(M + 31) / 32, tblk, 0, stream>>>(out_t, out, M);
    }
}

// Round 12
// 135.776 us; speedup vs baseline: 1.2327x; 1.1275x over previous
//
#include <hip/hip_runtime.h>

// SpMM: out[b,m] = bias[m] + sum_{e: dst[e]==m} values[e] * x[b, src[e]]
// B=32, N=M=50000, E=1600000.
// v12b (v12 resubmit; round-11 bench died at container level, no counters).
// Only change vs v12: hipMemsetAsync inside kernel_launch (the one new,
// potentially graph-capture-hostile call) replaced with the proven k_zero_i32
// dispatch. Theory unchanged: kill the sorted-CSR HBM round-trip (~51MB + a
// dispatch) by fusing sort+gather per bucket in LDS: stage segment (mean
// 4092x8B=32KB), build perm (count/wave-scan/scatter), 16-wave float4 row
// gather via stage[perm[]], LDS result tile, direct (B,M) write with bias.

#define BATCH 32
#define DPB   128             // dsts per bucket -> NB = 391
#define NB_MAX 400
#define BIN_TPB 1024
#define BIN_CHUNK 4096
#define BIN_EPT 4             // BIN_CHUNK / BIN_TPB
#define CAP   5120            // sort_gather LDS tile (entries); mean seg 4092

__global__ void k_zero_i32(int* __restrict__ p, int n) {
    const int i = blockIdx.x * blockDim.x + threadIdx.x;
    if (i < n) p[i] = 0;
}

// ---- fused: transpose x (B,N)->(N,B)  +  per-bucket histogram of dst ----
// blocks [0,TB): transpose role; blocks [TB, TB+CB): count role.
__global__ void k_tx_count(const float* __restrict__ x, float* __restrict__ xt, int N,
                           const int* __restrict__ idx, int E,
                           int* __restrict__ gcount, int NB, int TB) {
    __shared__ float tile[32][33];
    const int tx = threadIdx.x;   // 0..31
    const int ty = threadIdx.y;   // 0..7
    const int tid = ty * 32 + tx;
    if (blockIdx.x >= TB) {
        // count role: grid-stride histogram via LDS staging
        __shared__ int hist[NB_MAX];
        for (int i = tid; i < NB; i += 256) hist[i] = 0;
        __syncthreads();
        const int cb = blockIdx.x - TB;
        const int CB = gridDim.x - TB;
        const int stride = CB * 256;
        for (int e = cb * 256 + tid; e < E; e += stride) {
            atomicAdd(&hist[idx[E + e] >> 7], 1);   // /DPB (128)
        }
        __syncthreads();
        for (int i = tid; i < NB; i += 256) {
            if (hist[i]) atomicAdd(&gcount[i], hist[i]);
        }
        return;
    }
    const int n0 = blockIdx.x * 32;
    #pragma unroll
    for (int k = 0; k < 4; ++k) {
        const int b = ty + 8 * k;
        const int n = n0 + tx;
        tile[tx][b] = (n < N) ? x[(size_t)b * N + n] : 0.0f;
    }
    __syncthreads();
    #pragma unroll
    for (int k = 0; k < 4; ++k) {
        const int n = n0 + ty + 8 * k;
        if (n < N) xt[(size_t)n * BATCH + tx] = tile[ty + 8 * k][tx];
    }
}

// ---- single-wg exclusive scan of bucket counts (NB <= 1024) ----
__global__ __launch_bounds__(1024) void k_scan_buckets(const int* __restrict__ gcount,
                                                       int* __restrict__ bucket_base,
                                                       int* __restrict__ gcursor,
                                                       int NB, int E) {
    __shared__ int s[1024];
    const int tid = threadIdx.x;
    const int v = (tid < NB) ? gcount[tid] : 0;
    s[tid] = v;
    __syncthreads();
    for (int off = 1; off < 1024; off <<= 1) {
        const int t = (tid >= off) ? s[tid - off] : 0;
        __syncthreads();
        s[tid] += t;
        __syncthreads();
    }
    if (tid < NB) {
        const int excl = s[tid] - v;
        bucket_base[tid] = excl;
        gcursor[tid] = excl;
    }
    if (tid == 0) bucket_base[NB] = E;
}

// ---- bin: LDS counting-sort each chunk by bucket, coalesced write-out ----
__global__ __launch_bounds__(BIN_TPB) void k_bin(const int* __restrict__ idx,
                                                 const float* __restrict__ values,
                                                 int* __restrict__ gcursor,
                                                 int2* __restrict__ sv,
                                                 int E, int NB) {
    __shared__ int  hist[NB_MAX];     // counts, then per-bucket cursor
    __shared__ int  loff[NB_MAX];     // chunk-local exclusive offsets
    __shared__ int  gbase[NB_MAX];    // this chunk's global segment base
    __shared__ int2 svl[BIN_CHUNK];   // chunk sorted by bucket (32 KB)
    __shared__ int  gidx[BIN_CHUNK];  // final global index per slot (16 KB)
    const int tid = threadIdx.x;
    if (tid < NB) hist[tid] = 0;
    __syncthreads();

    const int c0 = blockIdx.x * BIN_CHUNK;
    const int nE = min(BIN_CHUNK, E - c0);
    int d[BIN_EPT];
    #pragma unroll
    for (int i = 0; i < BIN_EPT; ++i) {
        const int e = c0 + tid + i * BIN_TPB;
        d[i] = (e < E) ? idx[E + e] : -1;
        if (d[i] >= 0) atomicAdd(&hist[d[i] >> 7], 1);
    }
    __syncthreads();
    // wave 0: exclusive scan of NB counts (64-lane chunks with carry)
    if (tid < 64) {
        int carry = 0;
        for (int c = 0; c < NB; c += 64) {
            const int j = c + tid;
            const int v = (j < NB) ? hist[j] : 0;
            int inc = v;
            #pragma unroll
            for (int dlt = 1; dlt < 64; dlt <<= 1) {
                const int t = __shfl_up(inc, dlt, 64);
                if (tid >= dlt) inc += t;
            }
            if (j < NB) loff[j] = carry + inc - v;
            carry += __shfl(inc, 63, 64);
        }
    }
    __syncthreads();
    // reserve global segments; reset cursors
    if (tid < NB) {
        const int c = hist[tid];
        gbase[tid] = c ? atomicAdd(&gcursor[tid], c) : 0;
        hist[tid] = 0;
    }
    __syncthreads();
    // scatter into LDS sorted order + record final global index
    #pragma unroll
    for (int i = 0; i < BIN_EPT; ++i) {
        if (d[i] >= 0) {
            const int e = c0 + tid + i * BIN_TPB;
            const int bkt = d[i] >> 7;
            const int off = atomicAdd(&hist[bkt], 1);
            const int slot = loff[bkt] + off;
            const int packed = (idx[e] & 0xFFFF) | ((d[i] & 127) << 16);
            svl[slot]  = make_int2(packed, __float_as_int(values[e]));
            gidx[slot] = gbase[bkt] + off;
        }
    }
    __syncthreads();
    // coalesced write-out: consecutive slots -> consecutive global addresses
    for (int s = tid; s < nE; s += BIN_TPB) {
        sv[gidx[s]] = svl[s];
    }
}

// ---- fused sort+gather: one block per bucket; stage segment in LDS, build
// perm (count/scan/scatter), 16 waves x 8 rows float4 gather, write out ----
__global__ __launch_bounds__(1024) void k_sort_gather(const int2* __restrict__ sv,
                                                      const int* __restrict__ bbase,
                                                      const float* __restrict__ xt,
                                                      const float* __restrict__ bias,
                                                      float* __restrict__ out, int M) {
    __shared__ int2 stage[CAP];             // 40 KB
    __shared__ unsigned short perm[CAP];    // 10 KB
    __shared__ int cnt[DPB];
    __shared__ int off[DPB + 1];
    __shared__ int cur[DPB];
    __shared__ float tile[DPB][33];         // 16.9 KB result accumulator

    const int bkt = blockIdx.x;
    const int beg = bbase[bkt];
    const int end = bbase[bkt + 1];
    const int tid = threadIdx.x;
    const int w    = tid >> 6;    // wave 0..15
    const int lane = tid & 63;
    const int g    = lane >> 3;   // 0..7 edge slot
    const int j    = lane & 7;    // 16B slice of the 128B xt row
    const int m0   = bkt * DPB;
    const float4* __restrict__ xt4 = (const float4*)xt;

    for (int i = tid; i < DPB * 33; i += 1024) ((float*)tile)[i] = 0.0f;

    for (int t0 = beg; t0 < end; t0 += CAP) {
        const int nE = min(CAP, end - t0);
        __syncthreads();            // tile-zero done / previous tile consumed
        if (tid < DPB) cnt[tid] = 0;
        __syncthreads();
        // load segment tile + count rows
        for (int i = tid; i < nE; i += 1024) {
            const int2 a = sv[t0 + i];
            stage[i] = a;
            atomicAdd(&cnt[(a.x >> 16) & 127], 1);
        }
        __syncthreads();
        if (tid < 64) {   // wave 0: scan 128 counts (two 64-chunks with carry)
            int carry = 0;
            #pragma unroll
            for (int c = 0; c < DPB; c += 64) {
                const int jj = c + tid;
                const int v = cnt[jj];
                int inc = v;
                #pragma unroll
                for (int dlt = 1; dlt < 64; dlt <<= 1) {
                    const int t = __shfl_up(inc, dlt, 64);
                    if (tid >= dlt) inc += t;
                }
                off[jj] = carry + inc - v;
                cur[jj] = carry + inc - v;
                carry += __shfl(inc, 63, 64);
            }
            if (tid == 0) off[DPB] = carry;
        }
        __syncthreads();
        // build permutation
        for (int i = tid; i < nE; i += 1024) {
            const int dl = (stage[i].x >> 16) & 127;
            const int p = atomicAdd(&cur[dl], 1);
            perm[p] = (unsigned short)i;
        }
        __syncthreads();
        // gather: wave w handles rows w, w+16, ..., w+112
        #pragma unroll
        for (int k = 0; k < DPB / 16; ++k) {
            const int r  = w + 16 * k;
            const int rb = off[r];
            const int re = off[r + 1];
            float ax = 0.f, ay = 0.f, az = 0.f, aw_ = 0.f;
            float bx = 0.f, by = 0.f, bz = 0.f, bw = 0.f;
            int q = rb;
            for (; q + 15 < re; q += 16) {   // 2 chains x 8 edges
                const int2 eA = stage[perm[q + g]];
                const int2 eB = stage[perm[q + 8 + g]];
                const float4 xA = xt4[(size_t)(eA.x & 0xFFFF) * 8 + j];
                const float4 xB = xt4[(size_t)(eB.x & 0xFFFF) * 8 + j];
                const float vA = __int_as_float(eA.y);
                const float vB = __int_as_float(eB.y);
                ax += vA * xA.x; ay += vA * xA.y; az += vA * xA.z; aw_ += vA * xA.w;
                bx += vB * xB.x; by += vB * xB.y; bz += vB * xB.z; bw  += vB * xB.w;
            }
            for (; q < re; q += 8) {         // ragged tail, predicated per group
                if (q + g < re) {
                    const int2 e = stage[perm[q + g]];
                    const float4 xv = xt4[(size_t)(e.x & 0xFFFF) * 8 + j];
                    const float v = __int_as_float(e.y);
                    ax += v * xv.x; ay += v * xv.y; az += v * xv.z; aw_ += v * xv.w;
                }
            }
            ax += bx; ay += by; az += bz; aw_ += bw;
            #pragma unroll
            for (int d = 8; d < 64; d <<= 1) {
                ax  += __shfl_xor(ax, d, 64);
                ay  += __shfl_xor(ay, d, 64);
                az  += __shfl_xor(az, d, 64);
                aw_ += __shfl_xor(aw_, d, 64);
            }
            if (g == 0) {   // lanes j=0..7 hold the row's 32 floats
                tile[r][j * 4 + 0] += ax;
                tile[r][j * 4 + 1] += ay;
                tile[r][j * 4 + 2] += az;
                tile[r][j * 4 + 3] += aw_;
            }
        }
    }
    __syncthreads();
    // write out (B,M) + bias: i = b*128 + c; consecutive tid -> consecutive m
    for (int i = tid; i < 32 * DPB; i += 1024) {
        const int b = i >> 7;
        const int c = i & 127;
        const int m2 = m0 + c;
        if (m2 < M) out[(size_t)b * M + m2] = tile[c][b] + bias[m2];
    }
}

// ---- fallback (atomic) path ----
__global__ void k_init_out_t(const float* __restrict__ bias, float* __restrict__ out_t, int M) {
    const int i = blockIdx.x * blockDim.x + threadIdx.x;
    if (i < M * BATCH) out_t[i] = bias[i >> 5];
}

__global__ void k_scatter(const float* __restrict__ xt, const float* __restrict__ values,
                          const int* __restrict__ idx, float* __restrict__ out_t, int E) {
    const int t = blockIdx.x * blockDim.x + threadIdx.x;
    const int e = t >> 5;
    const int b = t & 31;
    if (e < E) {
        const int src = idx[e];
        const int dst = idx[E + e];
        const float contrib = values[e] * xt[(size_t)src * BATCH + b];
        atomicAdd(&out_t[(size_t)dst * BATCH + b], contrib);
    }
}

__global__ void k_transpose_out(const float* __restrict__ out_t, float* __restrict__ out, int M) {
    __shared__ float tile[32][33];
    const int m0 = blockIdx.x * 32;
    const int tx = threadIdx.x;
    const int ty = threadIdx.y;
    #pragma unroll
    for (int k = 0; k < 4; ++k) {
        const int m = m0 + ty + 8 * k;
        if (m < M) tile[ty + 8 * k][tx] = out_t[(size_t)m * BATCH + tx];
    }
    __syncthreads();
    #pragma unroll
    for (int k = 0; k < 4; ++k) {
        const int b = ty + 8 * k;
        const int m = m0 + tx;
        if (m < M) out[(size_t)b * M + m] = tile[tx][b];
    }
}

extern "C" void kernel_launch(void* const* d_in, const int* in_sizes, int n_in,
                              void* d_out, int out_size, void* d_ws, size_t ws_size,
                              hipStream_t stream) {
    const float* x      = (const float*)d_in[0];  // (B,N,1) fp32
    const float* values = (const float*)d_in[1];  // (E,)    fp32
    const float* bias   = (const float*)d_in[2];  // (M,1)   fp32
    const int*   idx    = (const int*)d_in[3];    // (2,E)   int32

    const int N = in_sizes[0] / BATCH;   // 50000
    const int E = in_sizes[3] / 2;       // 1600000
    const int M = in_sizes[2];           // 50000
    const int NB = (M + DPB - 1) / DPB;  // 391

    float* out = (float*)d_out;

    // ---- workspace carve (512B aligned); fallback needs only xt+out_t ----
    char* base = (char*)d_ws;
    size_t off = 0;
    auto carve = [&](size_t bytes) -> void* {
        void* r = base + off;
        off = (off + bytes + 511) & ~(size_t)511;
        return r;
    };
    float* xt      = (float*)carve((size_t)N * BATCH * sizeof(float));  // 6.4 MB
    float* out_t   = (float*)carve((size_t)M * BATCH * sizeof(float));  // 6.4 MB
    int2*  sv      = (int2*)carve((size_t)E * sizeof(int2));            // 12.8 MB
    int*   gcount  = (int*)carve((size_t)NB * sizeof(int));
    int*   bbase   = (int*)carve((size_t)(NB + 1) * sizeof(int));
    int*   gcursor = (int*)carve((size_t)NB * sizeof(int));
    const size_t csr_needed = off;

    dim3 tblk(32, 8);
    const int TB = (N + 31) / 32;

    const bool use_csr = (csr_needed <= ws_size) && (N <= 65536) && (M <= 65536)
                         && (NB <= NB_MAX);
    if (use_csr) {
        k_zero_i32<<<(NB + 255) / 256, 256, 0, stream>>>(gcount, NB);
        k_tx_count<<<TB + 512, tblk, 0, stream>>>(x, xt, N, idx, E, gcount, NB, TB);
        k_scan_buckets<<<1, 1024, 0, stream>>>(gcount, bbase, gcursor, NB, E);
        k_bin<<<(E + BIN_CHUNK - 1) / BIN_CHUNK, BIN_TPB, 0, stream>>>(idx, values, gcursor, sv, E, NB);
        k_sort_gather<<<NB, 1024, 0, stream>>>(sv, bbase, xt, bias, out, M);
    } else {
        // fallback: proven atomic path
        k_tx_count<<<TB, tblk, 0, stream>>>(x, xt, N, idx, E, gcount, NB, TB);
        k_init_out_t<<<(M * BATCH + 255) / 256, 256, 0, stream>>>(bias, out_t, M);
        const long long total = (long long)E * BATCH;
        k_scatter<<<(int)((total + 255) / 256), 256, 0, stream>>>(xt, values, idx, out_t, E);
        k_transpose_out<<<(M + 31) / 32, tblk, 0, stream>>>(out_t, out, M);
    }
}